// Round 10
// baseline (245.476 us; speedup 1.0000x reference)
//
#include <hip/hip_runtime.h>
#include <math.h>

#define NN 50000
#define NE 800000
#define DD 128
#define LL 4
#define OUTD 40
#define SCAN_NB ((NN + 255) / 256)   // 196
#define NPART 8
#define PART_SZ ((NN + NPART - 1) / NPART)   // 6250
#define NCHUNK 256
#define CHUNK_E (NE / NCHUNK)                // 3125

// S(t) = sigmoid(10*(elu(t) - 0.5)), matching jax.nn.elu (expm1) + sigmoid
__device__ __forceinline__ float S_func(float t) {
    float z = (t > 0.0f) ? t : expm1f(t);
    float xx = 10.0f * (z - 0.5f);
    return 1.0f / (1.0f + expf(-xx));
}

// T0[l*128+d][j] and Delta[(l*128+d)*10 + (c-1)][j]
__global__ void build_T(const float* __restrict__ W_layers,
                        float* __restrict__ T0, float* __restrict__ Delta) {
    int bd = blockIdx.x;           // l*128 + d
    int l = bd >> 7, d = bd & 127;
    int j = threadIdx.x;
    const float* W2 = W_layers + ((size_t)l * 1408 + 128 + (size_t)d * 10) * 128;
    float w[10];
    #pragma unroll
    for (int y = 0; y < 10; ++y) w[y] = W2[(size_t)y * 128 + j];
    float t0 = 0.0f;
    #pragma unroll
    for (int y = 0; y < 10; ++y) t0 += S_func((float)(0 - y)) * w[y];
    T0[(size_t)bd * 128 + j] = t0;
    for (int c = 1; c <= 10; ++c) {
        float tc = 0.0f;
        #pragma unroll
        for (int y = 0; y < 10; ++y) tc += S_func((float)(c - y)) * w[y];
        Delta[((size_t)bd * 10 + (c - 1)) * 128 + j] = tc - t0;
    }
}

__global__ void build_Base(const float* __restrict__ T0, float* __restrict__ Base) {
    int l = blockIdx.x, j = threadIdx.x;
    float s = 0.0f;
    for (int d = 0; d < 128; ++d) s += T0[((size_t)l * 128 + d) * 128 + j];
    Base[l * 128 + j] = s;
}

// ---- input GEMM: 256 thr, 32 nodes x 128 cols per block, 4 nodes x 4 cols
// per thread. cg = t&31 -> cols cg*4..cg*4+3 (one ds_read_b128 per k);
// ng = t>>5 -> nodes n0+ng*4+i. Ratio: 1 B LDS per FMA (nodes/thread=4 sets
// it); 400K threads -> 6.1 waves/SIMD (cols/thread=4 maximizes TLP).
// Per-(n,j) FMA chain is k-ascending, single accumulator -> bit-identical
// to all passing rounds; argmax is max-with-min-index (mapping-independent).
__global__ __launch_bounds__(256, 6) void input_kernel(const float* __restrict__ x,
        const float* __restrict__ W_in, const float* __restrict__ b_in,
        int* __restrict__ idx0) {
    __shared__ float wlds[32][128];
    int t = threadIdx.x;
    int cg = t & 31;
    int ng = t >> 5;
    int n0 = blockIdx.x * 32;
    const float* xp[4];
    #pragma unroll
    for (int i = 0; i < 4; ++i) {
        int n = n0 + ng * 4 + i;
        if (n > NN - 1) n = NN - 1;
        xp[i] = x + (size_t)n * 128;
    }
    float acc[4][4];
    #pragma unroll
    for (int i = 0; i < 4; ++i)
        #pragma unroll
        for (int r = 0; r < 4; ++r) acc[i][r] = 0.0f;

    for (int kc = 0; kc < 4; ++kc) {
        __syncthreads();
        #pragma unroll
        for (int p = 0; p < 4; ++p) {
            int f = t + p * 256;           // float4 id in [0,1024)
            int kr = f >> 5, c4 = f & 31;
            *(float4*)&wlds[kr][c4 * 4] =
                *(const float4*)&W_in[(size_t)(kc * 32 + kr) * 128 + c4 * 4];
        }
        __syncthreads();
        float4 xc[4];
        #pragma unroll
        for (int i = 0; i < 4; ++i) xc[i] = *(const float4*)(xp[i] + kc * 32);
        #pragma unroll
        for (int kk4 = 0; kk4 < 8; ++kk4) {
            float4 xn[4];
            if (kk4 < 7) {
                #pragma unroll
                for (int i = 0; i < 4; ++i)
                    xn[i] = *(const float4*)(xp[i] + kc * 32 + kk4 * 4 + 4);
            }
            #pragma unroll
            for (int q = 0; q < 4; ++q) {
                int k = kk4 * 4 + q;
                float4 w1 = *(const float4*)&wlds[k][cg * 4];
                #pragma unroll
                for (int i = 0; i < 4; ++i) {
                    float xv = (q == 0) ? xc[i].x : (q == 1) ? xc[i].y
                             : (q == 2) ? xc[i].z : xc[i].w;
                    acc[i][0] = fmaf(xv, w1.x, acc[i][0]);
                    acc[i][1] = fmaf(xv, w1.y, acc[i][1]);
                    acc[i][2] = fmaf(xv, w1.z, acc[i][2]);
                    acc[i][3] = fmaf(xv, w1.w, acc[i][3]);
                }
            }
            if (kk4 < 7) {
                #pragma unroll
                for (int i = 0; i < 4; ++i) xc[i] = xn[i];
            }
        }
    }
    float4 b1 = *(const float4*)&b_in[cg * 4];
    #pragma unroll
    for (int i = 0; i < 4; ++i) {
        float v0 = acc[i][0] + b1.x, v1 = acc[i][1] + b1.y;
        float v2 = acc[i][2] + b1.z, v3 = acc[i][3] + b1.w;
        float bv = v0; int bi = cg * 4;
        if (v1 > bv) { bv = v1; bi = cg * 4 + 1; }
        if (v2 > bv) { bv = v2; bi = cg * 4 + 2; }
        if (v3 > bv) { bv = v3; bi = cg * 4 + 3; }
        #pragma unroll
        for (int o = 16; o >= 1; o >>= 1) {
            float ov = __shfl_xor(bv, o);
            int oi = __shfl_xor(bi, o);
            if (ov > bv || (ov == bv && oi < bi)) { bv = ov; bi = oi; }
        }
        int n = n0 + ng * 4 + i;
        if (cg == 0 && n < NN) idx0[n] = bi;
    }
}

// ---- CSR build (edge structure fixed; built once per call) ----
// deg histogram + per-edge rank capture (makes scatter atomic-free)
__global__ void deg_kernel(const int* __restrict__ dst, unsigned int* __restrict__ deg,
        unsigned int* __restrict__ pos_e) {
    int e = blockIdx.x * 256 + threadIdx.x;
    if (e < NE) pos_e[e] = atomicAdd(&deg[dst[e]], 1u);
}

// multi-block scan, phase 1: per-block sum of 256 deg entries
__global__ __launch_bounds__(256) void partial_kernel(const unsigned int* __restrict__ deg,
        unsigned int* __restrict__ blocksum) {
    __shared__ unsigned int wsum[4];
    int t = threadIdx.x;
    int i = blockIdx.x * 256 + t;
    int w = t >> 6, lane = t & 63;
    unsigned int v = (i < NN) ? deg[i] : 0u;
    #pragma unroll
    for (int o = 32; o >= 1; o >>= 1) v += __shfl_xor(v, o);
    if (lane == 0) wsum[w] = v;
    __syncthreads();
    if (t == 0) blocksum[blockIdx.x] = wsum[0] + wsum[1] + wsum[2] + wsum[3];
}

// phase 2: exclusive scan of SCAN_NB block sums (single small block)
__global__ __launch_bounds__(256) void scan_blocksums(const unsigned int* __restrict__ blocksum,
        unsigned int* __restrict__ blockoff) {
    __shared__ unsigned int wsum[4];
    int t = threadIdx.x;
    int w = t >> 6, lane = t & 63;
    unsigned int v = (t < SCAN_NB) ? blocksum[t] : 0u;
    unsigned int s = v;
    #pragma unroll
    for (int o = 1; o < 64; o <<= 1) {
        unsigned int u = __shfl_up(s, o, 64);
        if (lane >= o) s += u;
    }
    if (lane == 63) wsum[w] = s;
    __syncthreads();
    unsigned int pre = 0;
    for (int k = 0; k < w; ++k) pre += wsum[k];
    if (t < SCAN_NB) blockoff[t] = pre + s - v;   // exclusive
}

// phase 3: block-level inclusive scan + block offset -> rowptr[i+1]; rowptr[0]=0
__global__ __launch_bounds__(256) void final_scan(const unsigned int* __restrict__ deg,
        const unsigned int* __restrict__ blockoff, unsigned int* __restrict__ rowptr) {
    __shared__ unsigned int wsum[4];
    int t = threadIdx.x;
    int i = blockIdx.x * 256 + t;
    int w = t >> 6, lane = t & 63;
    unsigned int v = (i < NN) ? deg[i] : 0u;
    unsigned int s = v;
    #pragma unroll
    for (int o = 1; o < 64; o <<= 1) {
        unsigned int u = __shfl_up(s, o, 64);
        if (lane >= o) s += u;
    }
    if (lane == 63) wsum[w] = s;
    __syncthreads();
    unsigned int pre = blockoff[blockIdx.x];
    for (int k = 0; k < w; ++k) pre += wsum[k];
    if (i < NN) rowptr[i + 1] = pre + s;
    if (i == 0) rowptr[0] = 0u;
}

// XCD-partitioned, atomic-free scatter: block b -> dst partition (b&7), edge
// chunk (b>>3). Writes to a given col line come from one XCD only (kills the
// R6 16x write amplification). pos_e precomputed by deg_kernel.
__global__ __launch_bounds__(256) void scatter_kernel(const int* __restrict__ src,
        const int* __restrict__ dst, const unsigned int* __restrict__ rowptr,
        const unsigned int* __restrict__ pos_e, int* __restrict__ col) {
    int part = blockIdx.x & (NPART - 1);
    int chunk = blockIdx.x >> 3;
    int lo = part * PART_SZ, hi = lo + PART_SZ;
    int e0 = chunk * CHUNK_E;
    int e1 = e0 + CHUNK_E;
    for (int e = e0 + threadIdx.x; e < e1; e += 256) {
        int d = dst[e];
        int s = src[e];                 // hoisted: coalesced reads
        unsigned int p = pos_e[e];
        if (d >= lo && d < hi) col[rowptr[d] + p] = s;
    }
}

// ---- fused per-layer kernel: half-wave (32 lanes) per node, float4 per lane ----
// 256 thr = 4 waves = 8 nodes per block; no __syncthreads needed (per-half-wave
// LDS regions; same-wave same-type LDS ops are program-ordered). cnt accessed
// ONLY as scalar uint (R3 lesson: vector-type punning + atomics -> TBAA reorder).
// Delta loop: 8-wide batched loads (8 in flight), adds ascending-i -> identical
// FP sequence to the serial loop.
__global__ __launch_bounds__(256) void layer_kernel(
        const unsigned int* __restrict__ rowptr, const int* __restrict__ col,
        const float* __restrict__ Wl, const float* __restrict__ bl,
        const float* __restrict__ Delta_l, const float* __restrict__ Base_l,
        const int* __restrict__ idx_in, int* __restrict__ idx_out) {
    __shared__ unsigned int cnt[8][128];
    __shared__ int list[8][128];
    int w = threadIdx.x >> 6;
    int lane = threadIdx.x & 63;
    int h = lane >> 5, l = lane & 31;
    int nidx = w * 2 + h;
    int n = blockIdx.x * 8 + nidx;
    // issue long-latency independent loads first
    unsigned int rs = rowptr[n], re = rowptr[n + 1];
    int hidx = idx_in[n];
    float4 wv = *(const float4*)((const char*)Wl + (size_t)hidx * 512 + l * 16);
    float4 bs = *(const float4*)((const char*)Base_l + l * 16);
    float4 bb = *(const float4*)((const char*)bl + l * 16);
    cnt[nidx][l]      = 0u;
    cnt[nidx][l + 32] = 0u;
    cnt[nidx][l + 64] = 0u;
    cnt[nidx][l + 96] = 0u;
    for (unsigned int e = rs + l; e < re; e += 32u) {
        int s = col[e];
        atomicAdd(&cnt[nidx][idx_in[s]], 1u);
    }
    unsigned int c0 = cnt[nidx][4 * l];
    unsigned int c1 = cnt[nidx][4 * l + 1];
    unsigned int c2 = cnt[nidx][4 * l + 2];
    unsigned int c3 = cnt[nidx][4 * l + 3];
    int f0 = c0 != 0u, f1 = c1 != 0u, f2 = c2 != 0u, f3 = c3 != 0u;
    int nb = f0 + f1 + f2 + f3;
    int incl = nb;
    #pragma unroll
    for (int o = 1; o < 32; o <<= 1) {
        int u = __shfl_up(incl, o, 32);
        if (l >= o) incl += u;
    }
    int pos = incl - nb;
    int total = __shfl(incl, 31, 32);
    if (f0) { unsigned int cc = c0 > 10u ? 10u : c0;
              list[nidx][pos++] = (int)(((4 * l + 0) * 10 + (int)cc - 1) * 512); }
    if (f1) { unsigned int cc = c1 > 10u ? 10u : c1;
              list[nidx][pos++] = (int)(((4 * l + 1) * 10 + (int)cc - 1) * 512); }
    if (f2) { unsigned int cc = c2 > 10u ? 10u : c2;
              list[nidx][pos++] = (int)(((4 * l + 2) * 10 + (int)cc - 1) * 512); }
    if (f3) { unsigned int cc = c3 > 10u ? 10u : c3;
              list[nidx][pos++] = (int)(((4 * l + 3) * 10 + (int)cc - 1) * 512); }
    float4 acc;
    acc.x = wv.x + bs.x;
    acc.y = wv.y + bs.y;
    acc.z = wv.z + bs.z;
    acc.w = wv.w + bs.w;
    const char* Db = (const char*)Delta_l + l * 16;
    int i = 0;
    for (; i + 8 <= total; i += 8) {
        int o0 = list[nidx][i];
        int o1 = list[nidx][i + 1];
        int o2 = list[nidx][i + 2];
        int o3 = list[nidx][i + 3];
        int o4 = list[nidx][i + 4];
        int o5 = list[nidx][i + 5];
        int o6 = list[nidx][i + 6];
        int o7 = list[nidx][i + 7];
        float4 d0 = *(const float4*)(Db + o0);
        float4 d1 = *(const float4*)(Db + o1);
        float4 d2 = *(const float4*)(Db + o2);
        float4 d3 = *(const float4*)(Db + o3);
        float4 d4 = *(const float4*)(Db + o4);
        float4 d5 = *(const float4*)(Db + o5);
        float4 d6 = *(const float4*)(Db + o6);
        float4 d7 = *(const float4*)(Db + o7);
        acc.x += d0.x; acc.y += d0.y; acc.z += d0.z; acc.w += d0.w;
        acc.x += d1.x; acc.y += d1.y; acc.z += d1.z; acc.w += d1.w;
        acc.x += d2.x; acc.y += d2.y; acc.z += d2.z; acc.w += d2.w;
        acc.x += d3.x; acc.y += d3.y; acc.z += d3.z; acc.w += d3.w;
        acc.x += d4.x; acc.y += d4.y; acc.z += d4.z; acc.w += d4.w;
        acc.x += d5.x; acc.y += d5.y; acc.z += d5.z; acc.w += d5.w;
        acc.x += d6.x; acc.y += d6.y; acc.z += d6.z; acc.w += d6.w;
        acc.x += d7.x; acc.y += d7.y; acc.z += d7.z; acc.w += d7.w;
    }
    for (; i + 4 <= total; i += 4) {
        int o0 = list[nidx][i];
        int o1 = list[nidx][i + 1];
        int o2 = list[nidx][i + 2];
        int o3 = list[nidx][i + 3];
        float4 d0 = *(const float4*)(Db + o0);
        float4 d1 = *(const float4*)(Db + o1);
        float4 d2 = *(const float4*)(Db + o2);
        float4 d3 = *(const float4*)(Db + o3);
        acc.x += d0.x; acc.y += d0.y; acc.z += d0.z; acc.w += d0.w;
        acc.x += d1.x; acc.y += d1.y; acc.z += d1.z; acc.w += d1.w;
        acc.x += d2.x; acc.y += d2.y; acc.z += d2.z; acc.w += d2.w;
        acc.x += d3.x; acc.y += d3.y; acc.z += d3.z; acc.w += d3.w;
    }
    for (; i < total; ++i) {
        float4 dv = *(const float4*)(Db + list[nidx][i]);
        acc.x += dv.x; acc.y += dv.y; acc.z += dv.z; acc.w += dv.w;
    }
    acc.x += bb.x; acc.y += bb.y; acc.z += bb.z; acc.w += bb.w;
    float bv = acc.x; int bi = 4 * l;
    if (acc.y > bv) { bv = acc.y; bi = 4 * l + 1; }
    if (acc.z > bv) { bv = acc.z; bi = 4 * l + 2; }
    if (acc.w > bv) { bv = acc.w; bi = 4 * l + 3; }
    #pragma unroll
    for (int o = 16; o >= 1; o >>= 1) {
        float ov = __shfl_xor(bv, o);
        int oi = __shfl_xor(bi, o);
        if (ov > bv || (ov == bv && oi < bi)) { bv = ov; bi = oi; }
    }
    if (l == 0) idx_out[n] = bi;
}

// logits: 4 nodes per 256-thr block, one wave per node (lanes 40-63 idle).
__global__ __launch_bounds__(256) void output_kernel(const int* __restrict__ idx,
        const float* __restrict__ W_out, const float* __restrict__ b_out,
        float* __restrict__ out) {
    int w = threadIdx.x >> 6;
    int o = threadIdx.x & 63;
    int n = blockIdx.x * 4 + w;
    if (n >= NN) return;
    float v;
    if (o < OUTD) {
        float a = 0.0f;
        #pragma unroll
        for (int l = 0; l < 5; ++l) {
            int id = idx[(size_t)l * NN + n];
            a += W_out[((size_t)(l * 128 + id)) * OUTD + o];
        }
        v = a + b_out[o];
    } else {
        v = -INFINITY;
    }
    float mx = v;
    #pragma unroll
    for (int s = 32; s >= 1; s >>= 1) mx = fmaxf(mx, __shfl_xor(mx, s));
    float e = (o < OUTD) ? expf(v - mx) : 0.0f;
    float se = e;
    #pragma unroll
    for (int s = 32; s >= 1; s >>= 1) se += __shfl_xor(se, s);
    if (o < OUTD) out[(size_t)n * OUTD + o] = v - mx - logf(se);
}

extern "C" void kernel_launch(void* const* d_in, const int* in_sizes, int n_in,
                              void* d_out, int out_size, void* d_ws, size_t ws_size,
                              hipStream_t stream) {
    const float* x        = (const float*)d_in[0];
    const int*   edge     = (const int*)d_in[1];   // [2, E] int32
    const float* W_in     = (const float*)d_in[2];
    const float* b_in     = (const float*)d_in[3];
    const float* W_layers = (const float*)d_in[4]; // [4, 1408, 128]
    const float* b_layers = (const float*)d_in[5];
    const float* W_out    = (const float*)d_in[6]; // [640, 40]
    const float* b_out    = (const float*)d_in[7];
    float* out = (float*)d_out;

    char* ws = (char*)d_ws;
    size_t off = 0;
    float* Delta = (float*)(ws + off); off += (size_t)LL * 128 * 10 * 128 * 4;
    float* T0    = (float*)(ws + off); off += (size_t)LL * 128 * 128 * 4;
    float* Base  = (float*)(ws + off); off += (size_t)LL * 128 * 4;
    int*   idx   = (int*)(ws + off);   off += (size_t)(LL + 1) * NN * 4;
    unsigned int* deg    = (unsigned int*)(ws + off); off += (size_t)NN * 4;
    unsigned int* rowptr = (unsigned int*)(ws + off); off += (size_t)(NN + 8) * 4;
    unsigned int* blocksum = (unsigned int*)(ws + off); off += 256 * 4;
    unsigned int* blockoff = (unsigned int*)(ws + off); off += 256 * 4;
    unsigned int* pos_e  = (unsigned int*)(ws + off); off += (size_t)NE * 4;
    int*   col   = (int*)(ws + off);   off += (size_t)NE * 4;

    const int* srcp = edge;
    const int* dstp = edge + NE;

    hipLaunchKernelGGL(build_T, dim3(LL * 128), dim3(128), 0, stream, W_layers, T0, Delta);
    hipLaunchKernelGGL(build_Base, dim3(LL), dim3(128), 0, stream, T0, Base);
    hipLaunchKernelGGL(input_kernel, dim3((NN + 31) / 32), dim3(256), 0, stream,
                       x, W_in, b_in, idx);

    hipMemsetAsync(deg, 0, (size_t)NN * 4, stream);
    hipLaunchKernelGGL(deg_kernel, dim3(NE / 256), dim3(256), 0, stream, dstp, deg, pos_e);
    hipLaunchKernelGGL(partial_kernel, dim3(SCAN_NB), dim3(256), 0, stream, deg, blocksum);
    hipLaunchKernelGGL(scan_blocksums, dim3(1), dim3(256), 0, stream, blocksum, blockoff);
    hipLaunchKernelGGL(final_scan, dim3(SCAN_NB), dim3(256), 0, stream, deg, blockoff, rowptr);
    hipLaunchKernelGGL(scatter_kernel, dim3(NPART * NCHUNK), dim3(256), 0, stream,
                       srcp, dstp, rowptr, pos_e, col);

    for (int l = 0; l < LL; ++l) {
        hipLaunchKernelGGL(layer_kernel, dim3(NN / 8), dim3(256), 0, stream,
                           rowptr, col,
                           W_layers + (size_t)l * 1408 * 128,
                           b_layers + (size_t)l * 128,
                           Delta + (size_t)l * 128 * 10 * 128,
                           Base + (size_t)l * 128,
                           idx + (size_t)l * NN,
                           idx + (size_t)(l + 1) * NN);
    }
    hipLaunchKernelGGL(output_kernel, dim3((NN + 3) / 4), dim3(256), 0, stream,
                       idx, W_out, b_out, out);
}

// Round 11
// 236.382 us; speedup vs baseline: 1.0385x; 1.0385x over previous
//
#include <hip/hip_runtime.h>
#include <math.h>

#define NN 50000
#define NE 800000
#define DD 128
#define LL 4
#define OUTD 40
#define SCAN_NB ((NN + 255) / 256)   // 196
#define NPART 8
#define PART_SZ ((NN + NPART - 1) / NPART)   // 6250
#define NCHUNK 256
#define CHUNK_E (NE / NCHUNK)                // 3125

// S(t) = sigmoid(10*(elu(t) - 0.5)), matching jax.nn.elu (expm1) + sigmoid
__device__ __forceinline__ float S_func(float t) {
    float z = (t > 0.0f) ? t : expm1f(t);
    float xx = 10.0f * (z - 0.5f);
    return 1.0f / (1.0f + expf(-xx));
}

// T0[l*128+d][j] and Delta[(l*128+d)*10 + (c-1)][j]
__global__ void build_T(const float* __restrict__ W_layers,
                        float* __restrict__ T0, float* __restrict__ Delta) {
    int bd = blockIdx.x;           // l*128 + d
    int l = bd >> 7, d = bd & 127;
    int j = threadIdx.x;
    const float* W2 = W_layers + ((size_t)l * 1408 + 128 + (size_t)d * 10) * 128;
    float w[10];
    #pragma unroll
    for (int y = 0; y < 10; ++y) w[y] = W2[(size_t)y * 128 + j];
    float t0 = 0.0f;
    #pragma unroll
    for (int y = 0; y < 10; ++y) t0 += S_func((float)(0 - y)) * w[y];
    T0[(size_t)bd * 128 + j] = t0;
    for (int c = 1; c <= 10; ++c) {
        float tc = 0.0f;
        #pragma unroll
        for (int y = 0; y < 10; ++y) tc += S_func((float)(c - y)) * w[y];
        Delta[((size_t)bd * 10 + (c - 1)) * 128 + j] = tc - t0;
    }
}

__global__ void build_Base(const float* __restrict__ T0, float* __restrict__ Base) {
    int l = blockIdx.x, j = threadIdx.x;
    float s = 0.0f;
    for (int d = 0; d < 128; ++d) s += T0[((size_t)l * 128 + d) * 128 + j];
    Base[l * 128 + j] = s;
}

// ---- input GEMM: 256 thr, 32 nodes x 128 cols per block, 4 nodes x 4 cols
// per thread; BOTH W and x staged in LDS per 32-k chunk so the inner loop is
// pure LDS + FMA (R10 lesson: global broadcast x-loads in the dependent chain
// stall the wave regardless of occupancy; R10's launch_bounds(,6) VGPR squeeze
// also killed ILP — no min-waves bound here).
// Per-(n,j) FMA chain: kc->kk4->q ascending, single accumulator ->
// bit-identical to all passing rounds. Argmax epilogue identical to R10.
__global__ __launch_bounds__(256) void input_kernel(const float* __restrict__ x,
        const float* __restrict__ W_in, const float* __restrict__ b_in,
        int* __restrict__ idx0) {
    __shared__ float wlds[32][128];
    __shared__ float xls[32][32];
    int t = threadIdx.x;
    int cg = t & 31;
    int ng = t >> 5;
    int n0 = blockIdx.x * 32;
    float acc[4][4];
    #pragma unroll
    for (int i = 0; i < 4; ++i)
        #pragma unroll
        for (int r = 0; r < 4; ++r) acc[i][r] = 0.0f;

    // x staging source addresses: thread t covers float4 (node = t>>3, k4 = t&7)
    int xn_node = t >> 3;
    int xn_k4 = t & 7;
    int xn_g = n0 + xn_node;
    if (xn_g > NN - 1) xn_g = NN - 1;
    const float* xsrc = x + (size_t)xn_g * 128 + xn_k4 * 4;

    for (int kc = 0; kc < 4; ++kc) {
        __syncthreads();
        #pragma unroll
        for (int p = 0; p < 4; ++p) {
            int f = t + p * 256;           // float4 id in [0,1024)
            int kr = f >> 5, c4 = f & 31;
            *(float4*)&wlds[kr][c4 * 4] =
                *(const float4*)&W_in[(size_t)(kc * 32 + kr) * 128 + c4 * 4];
        }
        *(float4*)&xls[xn_node][xn_k4 * 4] = *(const float4*)(xsrc + kc * 32);
        __syncthreads();
        #pragma unroll
        for (int kk4 = 0; kk4 < 8; ++kk4) {
            float4 xv[4];
            #pragma unroll
            for (int i = 0; i < 4; ++i)
                xv[i] = *(const float4*)&xls[ng * 4 + i][kk4 * 4];
            #pragma unroll
            for (int q = 0; q < 4; ++q) {
                int k = kk4 * 4 + q;
                float4 w1 = *(const float4*)&wlds[k][cg * 4];
                #pragma unroll
                for (int i = 0; i < 4; ++i) {
                    float xvv = (q == 0) ? xv[i].x : (q == 1) ? xv[i].y
                              : (q == 2) ? xv[i].z : xv[i].w;
                    acc[i][0] = fmaf(xvv, w1.x, acc[i][0]);
                    acc[i][1] = fmaf(xvv, w1.y, acc[i][1]);
                    acc[i][2] = fmaf(xvv, w1.z, acc[i][2]);
                    acc[i][3] = fmaf(xvv, w1.w, acc[i][3]);
                }
            }
        }
    }
    float4 b1 = *(const float4*)&b_in[cg * 4];
    #pragma unroll
    for (int i = 0; i < 4; ++i) {
        float v0 = acc[i][0] + b1.x, v1 = acc[i][1] + b1.y;
        float v2 = acc[i][2] + b1.z, v3 = acc[i][3] + b1.w;
        float bv = v0; int bi = cg * 4;
        if (v1 > bv) { bv = v1; bi = cg * 4 + 1; }
        if (v2 > bv) { bv = v2; bi = cg * 4 + 2; }
        if (v3 > bv) { bv = v3; bi = cg * 4 + 3; }
        #pragma unroll
        for (int o = 16; o >= 1; o >>= 1) {
            float ov = __shfl_xor(bv, o);
            int oi = __shfl_xor(bi, o);
            if (ov > bv || (ov == bv && oi < bi)) { bv = ov; bi = oi; }
        }
        int n = n0 + ng * 4 + i;
        if (cg == 0 && n < NN) idx0[n] = bi;
    }
}

// ---- CSR build (edge structure fixed; built once per call) ----
// deg histogram + per-edge rank capture (makes scatter atomic-free)
__global__ void deg_kernel(const int* __restrict__ dst, unsigned int* __restrict__ deg,
        unsigned int* __restrict__ pos_e) {
    int e = blockIdx.x * 256 + threadIdx.x;
    if (e < NE) pos_e[e] = atomicAdd(&deg[dst[e]], 1u);
}

// multi-block scan, phase 1: per-block sum of 256 deg entries
__global__ __launch_bounds__(256) void partial_kernel(const unsigned int* __restrict__ deg,
        unsigned int* __restrict__ blocksum) {
    __shared__ unsigned int wsum[4];
    int t = threadIdx.x;
    int i = blockIdx.x * 256 + t;
    int w = t >> 6, lane = t & 63;
    unsigned int v = (i < NN) ? deg[i] : 0u;
    #pragma unroll
    for (int o = 32; o >= 1; o >>= 1) v += __shfl_xor(v, o);
    if (lane == 0) wsum[w] = v;
    __syncthreads();
    if (t == 0) blocksum[blockIdx.x] = wsum[0] + wsum[1] + wsum[2] + wsum[3];
}

// phase 2: exclusive scan of SCAN_NB block sums (single small block)
__global__ __launch_bounds__(256) void scan_blocksums(const unsigned int* __restrict__ blocksum,
        unsigned int* __restrict__ blockoff) {
    __shared__ unsigned int wsum[4];
    int t = threadIdx.x;
    int w = t >> 6, lane = t & 63;
    unsigned int v = (t < SCAN_NB) ? blocksum[t] : 0u;
    unsigned int s = v;
    #pragma unroll
    for (int o = 1; o < 64; o <<= 1) {
        unsigned int u = __shfl_up(s, o, 64);
        if (lane >= o) s += u;
    }
    if (lane == 63) wsum[w] = s;
    __syncthreads();
    unsigned int pre = 0;
    for (int k = 0; k < w; ++k) pre += wsum[k];
    if (t < SCAN_NB) blockoff[t] = pre + s - v;   // exclusive
}

// phase 3: block-level inclusive scan + block offset -> rowptr[i+1]; rowptr[0]=0
__global__ __launch_bounds__(256) void final_scan(const unsigned int* __restrict__ deg,
        const unsigned int* __restrict__ blockoff, unsigned int* __restrict__ rowptr) {
    __shared__ unsigned int wsum[4];
    int t = threadIdx.x;
    int i = blockIdx.x * 256 + t;
    int w = t >> 6, lane = t & 63;
    unsigned int v = (i < NN) ? deg[i] : 0u;
    unsigned int s = v;
    #pragma unroll
    for (int o = 1; o < 64; o <<= 1) {
        unsigned int u = __shfl_up(s, o, 64);
        if (lane >= o) s += u;
    }
    if (lane == 63) wsum[w] = s;
    __syncthreads();
    unsigned int pre = blockoff[blockIdx.x];
    for (int k = 0; k < w; ++k) pre += wsum[k];
    if (i < NN) rowptr[i + 1] = pre + s;
    if (i == 0) rowptr[0] = 0u;
}

// XCD-partitioned, atomic-free scatter: block b -> dst partition (b&7), edge
// chunk (b>>3). Writes to a given col line come from one XCD only (kills the
// R6 16x write amplification). pos_e precomputed by deg_kernel.
__global__ __launch_bounds__(256) void scatter_kernel(const int* __restrict__ src,
        const int* __restrict__ dst, const unsigned int* __restrict__ rowptr,
        const unsigned int* __restrict__ pos_e, int* __restrict__ col) {
    int part = blockIdx.x & (NPART - 1);
    int chunk = blockIdx.x >> 3;
    int lo = part * PART_SZ, hi = lo + PART_SZ;
    int e0 = chunk * CHUNK_E;
    int e1 = e0 + CHUNK_E;
    for (int e = e0 + threadIdx.x; e < e1; e += 256) {
        int d = dst[e];
        int s = src[e];                 // hoisted: coalesced reads
        unsigned int p = pos_e[e];
        if (d >= lo && d < hi) col[rowptr[d] + p] = s;
    }
}

// ---- fused per-layer kernel: half-wave (32 lanes) per node, float4 per lane ----
// 256 thr = 4 waves = 8 nodes per block; no __syncthreads needed (per-half-wave
// LDS regions; same-wave same-type LDS ops are program-ordered). cnt accessed
// ONLY as scalar uint (R3 lesson: vector-type punning + atomics -> TBAA reorder).
// Delta loop: 8-wide batched loads (8 in flight), adds ascending-i -> identical
// FP sequence to the serial loop.
__global__ __launch_bounds__(256) void layer_kernel(
        const unsigned int* __restrict__ rowptr, const int* __restrict__ col,
        const float* __restrict__ Wl, const float* __restrict__ bl,
        const float* __restrict__ Delta_l, const float* __restrict__ Base_l,
        const int* __restrict__ idx_in, int* __restrict__ idx_out) {
    __shared__ unsigned int cnt[8][128];
    __shared__ int list[8][128];
    int w = threadIdx.x >> 6;
    int lane = threadIdx.x & 63;
    int h = lane >> 5, l = lane & 31;
    int nidx = w * 2 + h;
    int n = blockIdx.x * 8 + nidx;
    // issue long-latency independent loads first
    unsigned int rs = rowptr[n], re = rowptr[n + 1];
    int hidx = idx_in[n];
    float4 wv = *(const float4*)((const char*)Wl + (size_t)hidx * 512 + l * 16);
    float4 bs = *(const float4*)((const char*)Base_l + l * 16);
    float4 bb = *(const float4*)((const char*)bl + l * 16);
    cnt[nidx][l]      = 0u;
    cnt[nidx][l + 32] = 0u;
    cnt[nidx][l + 64] = 0u;
    cnt[nidx][l + 96] = 0u;
    for (unsigned int e = rs + l; e < re; e += 32u) {
        int s = col[e];
        atomicAdd(&cnt[nidx][idx_in[s]], 1u);
    }
    unsigned int c0 = cnt[nidx][4 * l];
    unsigned int c1 = cnt[nidx][4 * l + 1];
    unsigned int c2 = cnt[nidx][4 * l + 2];
    unsigned int c3 = cnt[nidx][4 * l + 3];
    int f0 = c0 != 0u, f1 = c1 != 0u, f2 = c2 != 0u, f3 = c3 != 0u;
    int nb = f0 + f1 + f2 + f3;
    int incl = nb;
    #pragma unroll
    for (int o = 1; o < 32; o <<= 1) {
        int u = __shfl_up(incl, o, 32);
        if (l >= o) incl += u;
    }
    int pos = incl - nb;
    int total = __shfl(incl, 31, 32);
    if (f0) { unsigned int cc = c0 > 10u ? 10u : c0;
              list[nidx][pos++] = (int)(((4 * l + 0) * 10 + (int)cc - 1) * 512); }
    if (f1) { unsigned int cc = c1 > 10u ? 10u : c1;
              list[nidx][pos++] = (int)(((4 * l + 1) * 10 + (int)cc - 1) * 512); }
    if (f2) { unsigned int cc = c2 > 10u ? 10u : c2;
              list[nidx][pos++] = (int)(((4 * l + 2) * 10 + (int)cc - 1) * 512); }
    if (f3) { unsigned int cc = c3 > 10u ? 10u : c3;
              list[nidx][pos++] = (int)(((4 * l + 3) * 10 + (int)cc - 1) * 512); }
    float4 acc;
    acc.x = wv.x + bs.x;
    acc.y = wv.y + bs.y;
    acc.z = wv.z + bs.z;
    acc.w = wv.w + bs.w;
    const char* Db = (const char*)Delta_l + l * 16;
    int i = 0;
    for (; i + 8 <= total; i += 8) {
        int o0 = list[nidx][i];
        int o1 = list[nidx][i + 1];
        int o2 = list[nidx][i + 2];
        int o3 = list[nidx][i + 3];
        int o4 = list[nidx][i + 4];
        int o5 = list[nidx][i + 5];
        int o6 = list[nidx][i + 6];
        int o7 = list[nidx][i + 7];
        float4 d0 = *(const float4*)(Db + o0);
        float4 d1 = *(const float4*)(Db + o1);
        float4 d2 = *(const float4*)(Db + o2);
        float4 d3 = *(const float4*)(Db + o3);
        float4 d4 = *(const float4*)(Db + o4);
        float4 d5 = *(const float4*)(Db + o5);
        float4 d6 = *(const float4*)(Db + o6);
        float4 d7 = *(const float4*)(Db + o7);
        acc.x += d0.x; acc.y += d0.y; acc.z += d0.z; acc.w += d0.w;
        acc.x += d1.x; acc.y += d1.y; acc.z += d1.z; acc.w += d1.w;
        acc.x += d2.x; acc.y += d2.y; acc.z += d2.z; acc.w += d2.w;
        acc.x += d3.x; acc.y += d3.y; acc.z += d3.z; acc.w += d3.w;
        acc.x += d4.x; acc.y += d4.y; acc.z += d4.z; acc.w += d4.w;
        acc.x += d5.x; acc.y += d5.y; acc.z += d5.z; acc.w += d5.w;
        acc.x += d6.x; acc.y += d6.y; acc.z += d6.z; acc.w += d6.w;
        acc.x += d7.x; acc.y += d7.y; acc.z += d7.z; acc.w += d7.w;
    }
    for (; i + 4 <= total; i += 4) {
        int o0 = list[nidx][i];
        int o1 = list[nidx][i + 1];
        int o2 = list[nidx][i + 2];
        int o3 = list[nidx][i + 3];
        float4 d0 = *(const float4*)(Db + o0);
        float4 d1 = *(const float4*)(Db + o1);
        float4 d2 = *(const float4*)(Db + o2);
        float4 d3 = *(const float4*)(Db + o3);
        acc.x += d0.x; acc.y += d0.y; acc.z += d0.z; acc.w += d0.w;
        acc.x += d1.x; acc.y += d1.y; acc.z += d1.z; acc.w += d1.w;
        acc.x += d2.x; acc.y += d2.y; acc.z += d2.z; acc.w += d2.w;
        acc.x += d3.x; acc.y += d3.y; acc.z += d3.z; acc.w += d3.w;
    }
    for (; i < total; ++i) {
        float4 dv = *(const float4*)(Db + list[nidx][i]);
        acc.x += dv.x; acc.y += dv.y; acc.z += dv.z; acc.w += dv.w;
    }
    acc.x += bb.x; acc.y += bb.y; acc.z += bb.z; acc.w += bb.w;
    float bv = acc.x; int bi = 4 * l;
    if (acc.y > bv) { bv = acc.y; bi = 4 * l + 1; }
    if (acc.z > bv) { bv = acc.z; bi = 4 * l + 2; }
    if (acc.w > bv) { bv = acc.w; bi = 4 * l + 3; }
    #pragma unroll
    for (int o = 16; o >= 1; o >>= 1) {
        float ov = __shfl_xor(bv, o);
        int oi = __shfl_xor(bi, o);
        if (ov > bv || (ov == bv && oi < bi)) { bv = ov; bi = oi; }
    }
    if (l == 0) idx_out[n] = bi;
}

// logits: 4 nodes per 256-thr block, one wave per node (lanes 40-63 idle).
__global__ __launch_bounds__(256) void output_kernel(const int* __restrict__ idx,
        const float* __restrict__ W_out, const float* __restrict__ b_out,
        float* __restrict__ out) {
    int w = threadIdx.x >> 6;
    int o = threadIdx.x & 63;
    int n = blockIdx.x * 4 + w;
    if (n >= NN) return;
    float v;
    if (o < OUTD) {
        float a = 0.0f;
        #pragma unroll
        for (int l = 0; l < 5; ++l) {
            int id = idx[(size_t)l * NN + n];
            a += W_out[((size_t)(l * 128 + id)) * OUTD + o];
        }
        v = a + b_out[o];
    } else {
        v = -INFINITY;
    }
    float mx = v;
    #pragma unroll
    for (int s = 32; s >= 1; s >>= 1) mx = fmaxf(mx, __shfl_xor(mx, s));
    float e = (o < OUTD) ? expf(v - mx) : 0.0f;
    float se = e;
    #pragma unroll
    for (int s = 32; s >= 1; s >>= 1) se += __shfl_xor(se, s);
    if (o < OUTD) out[(size_t)n * OUTD + o] = v - mx - logf(se);
}

extern "C" void kernel_launch(void* const* d_in, const int* in_sizes, int n_in,
                              void* d_out, int out_size, void* d_ws, size_t ws_size,
                              hipStream_t stream) {
    const float* x        = (const float*)d_in[0];
    const int*   edge     = (const int*)d_in[1];   // [2, E] int32
    const float* W_in     = (const float*)d_in[2];
    const float* b_in     = (const float*)d_in[3];
    const float* W_layers = (const float*)d_in[4]; // [4, 1408, 128]
    const float* b_layers = (const float*)d_in[5];
    const float* W_out    = (const float*)d_in[6]; // [640, 40]
    const float* b_out    = (const float*)d_in[7];
    float* out = (float*)d_out;

    char* ws = (char*)d_ws;
    size_t off = 0;
    float* Delta = (float*)(ws + off); off += (size_t)LL * 128 * 10 * 128 * 4;
    float* T0    = (float*)(ws + off); off += (size_t)LL * 128 * 128 * 4;
    float* Base  = (float*)(ws + off); off += (size_t)LL * 128 * 4;
    int*   idx   = (int*)(ws + off);   off += (size_t)(LL + 1) * NN * 4;
    unsigned int* deg    = (unsigned int*)(ws + off); off += (size_t)NN * 4;
    unsigned int* rowptr = (unsigned int*)(ws + off); off += (size_t)(NN + 8) * 4;
    unsigned int* blocksum = (unsigned int*)(ws + off); off += 256 * 4;
    unsigned int* blockoff = (unsigned int*)(ws + off); off += 256 * 4;
    unsigned int* pos_e  = (unsigned int*)(ws + off); off += (size_t)NE * 4;
    int*   col   = (int*)(ws + off);   off += (size_t)NE * 4;

    const int* srcp = edge;
    const int* dstp = edge + NE;

    hipLaunchKernelGGL(build_T, dim3(LL * 128), dim3(128), 0, stream, W_layers, T0, Delta);
    hipLaunchKernelGGL(build_Base, dim3(LL), dim3(128), 0, stream, T0, Base);
    hipLaunchKernelGGL(input_kernel, dim3((NN + 31) / 32), dim3(256), 0, stream,
                       x, W_in, b_in, idx);

    hipMemsetAsync(deg, 0, (size_t)NN * 4, stream);
    hipLaunchKernelGGL(deg_kernel, dim3(NE / 256), dim3(256), 0, stream, dstp, deg, pos_e);
    hipLaunchKernelGGL(partial_kernel, dim3(SCAN_NB), dim3(256), 0, stream, deg, blocksum);
    hipLaunchKernelGGL(scan_blocksums, dim3(1), dim3(256), 0, stream, blocksum, blockoff);
    hipLaunchKernelGGL(final_scan, dim3(SCAN_NB), dim3(256), 0, stream, deg, blockoff, rowptr);
    hipLaunchKernelGGL(scatter_kernel, dim3(NPART * NCHUNK), dim3(256), 0, stream,
                       srcp, dstp, rowptr, pos_e, col);

    for (int l = 0; l < LL; ++l) {
        hipLaunchKernelGGL(layer_kernel, dim3(NN / 8), dim3(256), 0, stream,
                           rowptr, col,
                           W_layers + (size_t)l * 1408 * 128,
                           b_layers + (size_t)l * 128,
                           Delta + (size_t)l * 128 * 10 * 128,
                           Base + (size_t)l * 128,
                           idx + (size_t)l * NN,
                           idx + (size_t)(l + 1) * NN);
    }
    hipLaunchKernelGGL(output_kernel, dim3((NN + 3) / 4), dim3(256), 0, stream,
                       idx, W_out, b_out, out);
}

// Round 12
// 198.062 us; speedup vs baseline: 1.2394x; 1.1935x over previous
//
#include <hip/hip_runtime.h>
#include <math.h>

#define NN 50000
#define NE 800000
#define DD 128
#define LL 4
#define OUTD 40
#define SCAN_NB ((NN + 255) / 256)   // 196
#define NPART 8
#define PART_SZ ((NN + NPART - 1) / NPART)   // 6250
#define NCHUNK 256
#define CHUNK_E (NE / NCHUNK)                // 3125
#define NB_T 256                              // build_T blocks (2 rows each)
#define NB_IN ((NN + 63) / 64)               // 782 input blocks
#define NB_DEG (NE / 256)                    // 3125 deg blocks

// S(t) = sigmoid(10*(elu(t) - 0.5)), matching jax.nn.elu (expm1) + sigmoid
__device__ __forceinline__ float S_func(float t) {
    float z = (t > 0.0f) ? t : expm1f(t);
    float xx = 10.0f * (z - 0.5f);
    return 1.0f / (1.0f + expf(-xx));
}

// ---- fused front kernel: build_T || input GEMM || deg histogram ----
// Independent phases dispatched by blockIdx range so they overlap on the
// machine instead of serializing as 3 launches (R11: fully serial chain).
__global__ __launch_bounds__(256) void front_kernel(
        const float* __restrict__ W_layers, float* __restrict__ T0,
        float* __restrict__ Delta,
        const float* __restrict__ x, const float* __restrict__ W_in,
        const float* __restrict__ b_in, int* __restrict__ idx0,
        const int* __restrict__ dst, unsigned int* __restrict__ deg,
        unsigned int* __restrict__ pos_e) {
    __shared__ float wlds[32][128];
    __shared__ float xls[64][32];
    int t = threadIdx.x;

    if (blockIdx.x < NB_T) {
        // ---- build_T: 2 (l,d) rows per block ----
        int bd = blockIdx.x * 2 + (t >> 7);
        int l = bd >> 7, d = bd & 127;
        int j = t & 127;
        const float* W2 = W_layers + ((size_t)l * 1408 + 128 + (size_t)d * 10) * 128;
        float w[10];
        #pragma unroll
        for (int y = 0; y < 10; ++y) w[y] = W2[(size_t)y * 128 + j];
        float t0 = 0.0f;
        #pragma unroll
        for (int y = 0; y < 10; ++y) t0 += S_func((float)(0 - y)) * w[y];
        T0[(size_t)bd * 128 + j] = t0;
        for (int c = 1; c <= 10; ++c) {
            float tc = 0.0f;
            #pragma unroll
            for (int y = 0; y < 10; ++y) tc += S_func((float)(c - y)) * w[y];
            Delta[((size_t)bd * 10 + (c - 1)) * 128 + j] = tc - t0;
        }
        return;
    }
    if (blockIdx.x >= NB_T + NB_IN) {
        // ---- deg histogram + per-edge rank ----
        int e = (blockIdx.x - NB_T - NB_IN) * 256 + t;
        if (e < NE) pos_e[e] = atomicAdd(&deg[dst[e]], 1u);
        return;
    }

    // ---- input GEMM: 64 nodes x 128 cols per block, 4 nodes x 8 cols/thread.
    // cg = t&15 -> cols {4cg..4cg+3} and {64+4cg..+3} (R5's proven layout);
    // ng = t>>4 -> nodes n0+ng*4+i. Both W and x staged in LDS: 12 b128 per
    // 128 FMAs = 1.5 B/FMA. Per-(n,j) chain kc->kk4->q ascending, single
    // accumulator -> bit-identical to all passing rounds.
    int bb = blockIdx.x - NB_T;
    int cg = t & 15;
    int ng = t >> 4;
    int n0 = bb * 64;
    float acc[4][8];
    #pragma unroll
    for (int i = 0; i < 4; ++i)
        #pragma unroll
        for (int r = 0; r < 8; ++r) acc[i][r] = 0.0f;

    // x staging: 512 float4s per chunk; thread t covers f = t, t+256
    for (int kc = 0; kc < 4; ++kc) {
        __syncthreads();
        #pragma unroll
        for (int p = 0; p < 4; ++p) {
            int f = t + p * 256;           // float4 id in [0,1024)
            int kr = f >> 5, c4 = f & 31;
            *(float4*)&wlds[kr][c4 * 4] =
                *(const float4*)&W_in[(size_t)(kc * 32 + kr) * 128 + c4 * 4];
        }
        #pragma unroll
        for (int p = 0; p < 2; ++p) {
            int f = t + p * 256;           // float4 id in [0,512)
            int node = f >> 3, k4 = f & 7;
            int gn = n0 + node;
            if (gn > NN - 1) gn = NN - 1;
            *(float4*)&xls[node][k4 * 4] =
                *(const float4*)&x[(size_t)gn * 128 + kc * 32 + k4 * 4];
        }
        __syncthreads();
        #pragma unroll
        for (int kk4 = 0; kk4 < 8; ++kk4) {
            float4 xv[4];
            #pragma unroll
            for (int i = 0; i < 4; ++i)
                xv[i] = *(const float4*)&xls[ng * 4 + i][kk4 * 4];
            #pragma unroll
            for (int q = 0; q < 4; ++q) {
                int k = kk4 * 4 + q;
                float4 w1 = *(const float4*)&wlds[k][cg * 4];
                float4 w2 = *(const float4*)&wlds[k][64 + cg * 4];
                #pragma unroll
                for (int i = 0; i < 4; ++i) {
                    float xvv = (q == 0) ? xv[i].x : (q == 1) ? xv[i].y
                              : (q == 2) ? xv[i].z : xv[i].w;
                    acc[i][0] = fmaf(xvv, w1.x, acc[i][0]);
                    acc[i][1] = fmaf(xvv, w1.y, acc[i][1]);
                    acc[i][2] = fmaf(xvv, w1.z, acc[i][2]);
                    acc[i][3] = fmaf(xvv, w1.w, acc[i][3]);
                    acc[i][4] = fmaf(xvv, w2.x, acc[i][4]);
                    acc[i][5] = fmaf(xvv, w2.y, acc[i][5]);
                    acc[i][6] = fmaf(xvv, w2.z, acc[i][6]);
                    acc[i][7] = fmaf(xvv, w2.w, acc[i][7]);
                }
            }
        }
    }
    float4 b1 = *(const float4*)&b_in[cg * 4];
    float4 b2 = *(const float4*)&b_in[64 + cg * 4];
    #pragma unroll
    for (int i = 0; i < 4; ++i) {
        float v0 = acc[i][0] + b1.x, v1 = acc[i][1] + b1.y;
        float v2 = acc[i][2] + b1.z, v3 = acc[i][3] + b1.w;
        float v4 = acc[i][4] + b2.x, v5 = acc[i][5] + b2.y;
        float v6 = acc[i][6] + b2.z, v7 = acc[i][7] + b2.w;
        float bv = v0; int bi = cg * 4;
        if (v1 > bv) { bv = v1; bi = cg * 4 + 1; }
        if (v2 > bv) { bv = v2; bi = cg * 4 + 2; }
        if (v3 > bv) { bv = v3; bi = cg * 4 + 3; }
        if (v4 > bv) { bv = v4; bi = 64 + cg * 4; }
        if (v5 > bv) { bv = v5; bi = 64 + cg * 4 + 1; }
        if (v6 > bv) { bv = v6; bi = 64 + cg * 4 + 2; }
        if (v7 > bv) { bv = v7; bi = 64 + cg * 4 + 3; }
        #pragma unroll
        for (int o = 8; o >= 1; o >>= 1) {
            float ov = __shfl_xor(bv, o);
            int oi = __shfl_xor(bi, o);
            if (ov > bv || (ov == bv && oi < bi)) { bv = ov; bi = oi; }
        }
        int n = n0 + ng * 4 + i;
        if (cg == 0 && n < NN) idx0[n] = bi;
    }
}

__global__ void build_Base(const float* __restrict__ T0, float* __restrict__ Base) {
    int l = blockIdx.x, j = threadIdx.x;
    float s = 0.0f;
    for (int d = 0; d < 128; ++d) s += T0[((size_t)l * 128 + d) * 128 + j];
    Base[l * 128 + j] = s;
}

// multi-block scan, phase 1: per-block sum of 256 deg entries
__global__ __launch_bounds__(256) void partial_kernel(const unsigned int* __restrict__ deg,
        unsigned int* __restrict__ blocksum) {
    __shared__ unsigned int wsum[4];
    int t = threadIdx.x;
    int i = blockIdx.x * 256 + t;
    int w = t >> 6, lane = t & 63;
    unsigned int v = (i < NN) ? deg[i] : 0u;
    #pragma unroll
    for (int o = 32; o >= 1; o >>= 1) v += __shfl_xor(v, o);
    if (lane == 0) wsum[w] = v;
    __syncthreads();
    if (t == 0) blocksum[blockIdx.x] = wsum[0] + wsum[1] + wsum[2] + wsum[3];
}

// phase 2 (merged): each block computes its own exclusive block offset from
// blocksum[0..blockIdx) (196 <= 256 values), then block-scans its deg chunk.
__global__ __launch_bounds__(256) void final_scan(const unsigned int* __restrict__ deg,
        const unsigned int* __restrict__ blocksum, unsigned int* __restrict__ rowptr) {
    __shared__ unsigned int wsum[4];
    __shared__ unsigned int presh;
    int t = threadIdx.x;
    int w = t >> 6, lane = t & 63;
    // block offset = sum of blocksum[k] for k < blockIdx
    unsigned int pv = (t < blockIdx.x) ? blocksum[t] : 0u;
    #pragma unroll
    for (int o = 32; o >= 1; o >>= 1) pv += __shfl_xor(pv, o);
    if (lane == 0) wsum[w] = pv;
    __syncthreads();
    if (t == 0) presh = wsum[0] + wsum[1] + wsum[2] + wsum[3];
    __syncthreads();
    unsigned int blockpre = presh;
    __syncthreads();   // wsum reused below
    int i = blockIdx.x * 256 + t;
    unsigned int v = (i < NN) ? deg[i] : 0u;
    unsigned int s = v;
    #pragma unroll
    for (int o = 1; o < 64; o <<= 1) {
        unsigned int u = __shfl_up(s, o, 64);
        if (lane >= o) s += u;
    }
    if (lane == 63) wsum[w] = s;
    __syncthreads();
    unsigned int pre = blockpre;
    for (int k = 0; k < w; ++k) pre += wsum[k];
    if (i < NN) rowptr[i + 1] = pre + s;
    if (i == 0) rowptr[0] = 0u;
}

// XCD-partitioned, atomic-free scatter: block b -> dst partition (b&7), edge
// chunk (b>>3). Writes to a given col line come from one XCD only (kills the
// R6 16x write amplification). pos_e precomputed in front_kernel.
__global__ __launch_bounds__(256) void scatter_kernel(const int* __restrict__ src,
        const int* __restrict__ dst, const unsigned int* __restrict__ rowptr,
        const unsigned int* __restrict__ pos_e, int* __restrict__ col) {
    int part = blockIdx.x & (NPART - 1);
    int chunk = blockIdx.x >> 3;
    int lo = part * PART_SZ, hi = lo + PART_SZ;
    int e0 = chunk * CHUNK_E;
    int e1 = e0 + CHUNK_E;
    for (int e = e0 + threadIdx.x; e < e1; e += 256) {
        int d = dst[e];
        int s = src[e];
        unsigned int p = pos_e[e];
        if (d >= lo && d < hi) col[rowptr[d] + p] = s;
    }
}

// ---- fused per-layer kernel: half-wave (32 lanes) per node, float4 per lane ----
// 256 thr = 4 waves = 8 nodes per block; no __syncthreads needed (per-half-wave
// LDS regions; same-wave same-type LDS ops are program-ordered). cnt accessed
// ONLY as scalar uint (R3 lesson: vector-type punning + atomics -> TBAA reorder).
// Delta loop: 8-wide batched loads, adds ascending-i -> identical FP sequence.
__global__ __launch_bounds__(256) void layer_kernel(
        const unsigned int* __restrict__ rowptr, const int* __restrict__ col,
        const float* __restrict__ Wl, const float* __restrict__ bl,
        const float* __restrict__ Delta_l, const float* __restrict__ Base_l,
        const int* __restrict__ idx_in, int* __restrict__ idx_out) {
    __shared__ unsigned int cnt[8][128];
    __shared__ int list[8][128];
    int w = threadIdx.x >> 6;
    int lane = threadIdx.x & 63;
    int h = lane >> 5, l = lane & 31;
    int nidx = w * 2 + h;
    int n = blockIdx.x * 8 + nidx;
    unsigned int rs = rowptr[n], re = rowptr[n + 1];
    int hidx = idx_in[n];
    float4 wv = *(const float4*)((const char*)Wl + (size_t)hidx * 512 + l * 16);
    float4 bs = *(const float4*)((const char*)Base_l + l * 16);
    float4 bb = *(const float4*)((const char*)bl + l * 16);
    cnt[nidx][l]      = 0u;
    cnt[nidx][l + 32] = 0u;
    cnt[nidx][l + 64] = 0u;
    cnt[nidx][l + 96] = 0u;
    for (unsigned int e = rs + l; e < re; e += 32u) {
        int s = col[e];
        atomicAdd(&cnt[nidx][idx_in[s]], 1u);
    }
    unsigned int c0 = cnt[nidx][4 * l];
    unsigned int c1 = cnt[nidx][4 * l + 1];
    unsigned int c2 = cnt[nidx][4 * l + 2];
    unsigned int c3 = cnt[nidx][4 * l + 3];
    int f0 = c0 != 0u, f1 = c1 != 0u, f2 = c2 != 0u, f3 = c3 != 0u;
    int nb = f0 + f1 + f2 + f3;
    int incl = nb;
    #pragma unroll
    for (int o = 1; o < 32; o <<= 1) {
        int u = __shfl_up(incl, o, 32);
        if (l >= o) incl += u;
    }
    int pos = incl - nb;
    int total = __shfl(incl, 31, 32);
    if (f0) { unsigned int cc = c0 > 10u ? 10u : c0;
              list[nidx][pos++] = (int)(((4 * l + 0) * 10 + (int)cc - 1) * 512); }
    if (f1) { unsigned int cc = c1 > 10u ? 10u : c1;
              list[nidx][pos++] = (int)(((4 * l + 1) * 10 + (int)cc - 1) * 512); }
    if (f2) { unsigned int cc = c2 > 10u ? 10u : c2;
              list[nidx][pos++] = (int)(((4 * l + 2) * 10 + (int)cc - 1) * 512); }
    if (f3) { unsigned int cc = c3 > 10u ? 10u : c3;
              list[nidx][pos++] = (int)(((4 * l + 3) * 10 + (int)cc - 1) * 512); }
    float4 acc;
    acc.x = wv.x + bs.x;
    acc.y = wv.y + bs.y;
    acc.z = wv.z + bs.z;
    acc.w = wv.w + bs.w;
    const char* Db = (const char*)Delta_l + l * 16;
    int i = 0;
    for (; i + 8 <= total; i += 8) {
        int o0 = list[nidx][i];
        int o1 = list[nidx][i + 1];
        int o2 = list[nidx][i + 2];
        int o3 = list[nidx][i + 3];
        int o4 = list[nidx][i + 4];
        int o5 = list[nidx][i + 5];
        int o6 = list[nidx][i + 6];
        int o7 = list[nidx][i + 7];
        float4 d0 = *(const float4*)(Db + o0);
        float4 d1 = *(const float4*)(Db + o1);
        float4 d2 = *(const float4*)(Db + o2);
        float4 d3 = *(const float4*)(Db + o3);
        float4 d4 = *(const float4*)(Db + o4);
        float4 d5 = *(const float4*)(Db + o5);
        float4 d6 = *(const float4*)(Db + o6);
        float4 d7 = *(const float4*)(Db + o7);
        acc.x += d0.x; acc.y += d0.y; acc.z += d0.z; acc.w += d0.w;
        acc.x += d1.x; acc.y += d1.y; acc.z += d1.z; acc.w += d1.w;
        acc.x += d2.x; acc.y += d2.y; acc.z += d2.z; acc.w += d2.w;
        acc.x += d3.x; acc.y += d3.y; acc.z += d3.z; acc.w += d3.w;
        acc.x += d4.x; acc.y += d4.y; acc.z += d4.z; acc.w += d4.w;
        acc.x += d5.x; acc.y += d5.y; acc.z += d5.z; acc.w += d5.w;
        acc.x += d6.x; acc.y += d6.y; acc.z += d6.z; acc.w += d6.w;
        acc.x += d7.x; acc.y += d7.y; acc.z += d7.z; acc.w += d7.w;
    }
    for (; i + 4 <= total; i += 4) {
        int o0 = list[nidx][i];
        int o1 = list[nidx][i + 1];
        int o2 = list[nidx][i + 2];
        int o3 = list[nidx][i + 3];
        float4 d0 = *(const float4*)(Db + o0);
        float4 d1 = *(const float4*)(Db + o1);
        float4 d2 = *(const float4*)(Db + o2);
        float4 d3 = *(const float4*)(Db + o3);
        acc.x += d0.x; acc.y += d0.y; acc.z += d0.z; acc.w += d0.w;
        acc.x += d1.x; acc.y += d1.y; acc.z += d1.z; acc.w += d1.w;
        acc.x += d2.x; acc.y += d2.y; acc.z += d2.z; acc.w += d2.w;
        acc.x += d3.x; acc.y += d3.y; acc.z += d3.z; acc.w += d3.w;
    }
    for (; i < total; ++i) {
        float4 dv = *(const float4*)(Db + list[nidx][i]);
        acc.x += dv.x; acc.y += dv.y; acc.z += dv.z; acc.w += dv.w;
    }
    acc.x += bb.x; acc.y += bb.y; acc.z += bb.z; acc.w += bb.w;
    float bv = acc.x; int bi = 4 * l;
    if (acc.y > bv) { bv = acc.y; bi = 4 * l + 1; }
    if (acc.z > bv) { bv = acc.z; bi = 4 * l + 2; }
    if (acc.w > bv) { bv = acc.w; bi = 4 * l + 3; }
    #pragma unroll
    for (int o = 16; o >= 1; o >>= 1) {
        float ov = __shfl_xor(bv, o);
        int oi = __shfl_xor(bi, o);
        if (ov > bv || (ov == bv && oi < bi)) { bv = ov; bi = oi; }
    }
    if (l == 0) idx_out[n] = bi;
}

// logits: 4 nodes per 256-thr block, one wave per node (lanes 40-63 idle).
__global__ __launch_bounds__(256) void output_kernel(const int* __restrict__ idx,
        const float* __restrict__ W_out, const float* __restrict__ b_out,
        float* __restrict__ out) {
    int w = threadIdx.x >> 6;
    int o = threadIdx.x & 63;
    int n = blockIdx.x * 4 + w;
    if (n >= NN) return;
    float v;
    if (o < OUTD) {
        float a = 0.0f;
        #pragma unroll
        for (int l = 0; l < 5; ++l) {
            int id = idx[(size_t)l * NN + n];
            a += W_out[((size_t)(l * 128 + id)) * OUTD + o];
        }
        v = a + b_out[o];
    } else {
        v = -INFINITY;
    }
    float mx = v;
    #pragma unroll
    for (int s = 32; s >= 1; s >>= 1) mx = fmaxf(mx, __shfl_xor(mx, s));
    float e = (o < OUTD) ? expf(v - mx) : 0.0f;
    float se = e;
    #pragma unroll
    for (int s = 32; s >= 1; s >>= 1) se += __shfl_xor(se, s);
    if (o < OUTD) out[(size_t)n * OUTD + o] = v - mx - logf(se);
}

extern "C" void kernel_launch(void* const* d_in, const int* in_sizes, int n_in,
                              void* d_out, int out_size, void* d_ws, size_t ws_size,
                              hipStream_t stream) {
    const float* x        = (const float*)d_in[0];
    const int*   edge     = (const int*)d_in[1];   // [2, E] int32
    const float* W_in     = (const float*)d_in[2];
    const float* b_in     = (const float*)d_in[3];
    const float* W_layers = (const float*)d_in[4]; // [4, 1408, 128]
    const float* b_layers = (const float*)d_in[5];
    const float* W_out    = (const float*)d_in[6]; // [640, 40]
    const float* b_out    = (const float*)d_in[7];
    float* out = (float*)d_out;

    char* ws = (char*)d_ws;
    size_t off = 0;
    float* Delta = (float*)(ws + off); off += (size_t)LL * 128 * 10 * 128 * 4;
    float* T0    = (float*)(ws + off); off += (size_t)LL * 128 * 128 * 4;
    float* Base  = (float*)(ws + off); off += (size_t)LL * 128 * 4;
    int*   idx   = (int*)(ws + off);   off += (size_t)(LL + 1) * NN * 4;
    unsigned int* deg    = (unsigned int*)(ws + off); off += (size_t)NN * 4;
    unsigned int* rowptr = (unsigned int*)(ws + off); off += (size_t)(NN + 8) * 4;
    unsigned int* blocksum = (unsigned int*)(ws + off); off += 256 * 4;
    unsigned int* pos_e  = (unsigned int*)(ws + off); off += (size_t)NE * 4;
    int*   col   = (int*)(ws + off);   off += (size_t)NE * 4;

    const int* srcp = edge;
    const int* dstp = edge + NE;

    hipMemsetAsync(deg, 0, (size_t)NN * 4, stream);
    hipLaunchKernelGGL(front_kernel, dim3(NB_T + NB_IN + NB_DEG), dim3(256), 0, stream,
                       W_layers, T0, Delta, x, W_in, b_in, idx, dstp, deg, pos_e);
    hipLaunchKernelGGL(build_Base, dim3(LL), dim3(128), 0, stream, T0, Base);
    hipLaunchKernelGGL(partial_kernel, dim3(SCAN_NB), dim3(256), 0, stream, deg, blocksum);
    hipLaunchKernelGGL(final_scan, dim3(SCAN_NB), dim3(256), 0, stream, deg, blocksum, rowptr);
    hipLaunchKernelGGL(scatter_kernel, dim3(NPART * NCHUNK), dim3(256), 0, stream,
                       srcp, dstp, rowptr, pos_e, col);

    for (int l = 0; l < LL; ++l) {
        hipLaunchKernelGGL(layer_kernel, dim3(NN / 8), dim3(256), 0, stream,
                           rowptr, col,
                           W_layers + (size_t)l * 1408 * 128,
                           b_layers + (size_t)l * 128,
                           Delta + (size_t)l * 128 * 10 * 128,
                           Base + (size_t)l * 128,
                           idx + (size_t)l * NN,
                           idx + (size_t)(l + 1) * NN);
    }
    hipLaunchKernelGGL(output_kernel, dim3((NN + 3) / 4), dim3(256), 0, stream,
                       idx, W_out, b_out, out);
}